// Round 1
// baseline (7951.003 us; speedup 1.0000x reference)
//
#include <hip/hip_runtime.h>

#define NA 512
#define NXX 512
#define MBATCH 64
#define TSTEPS 1024
#define MT (MBATCH * TSTEPS)       // 65536 flattened (m,t)
#define ASZ (NA * MBATCH * TSTEPS) // 33554432 elements per output tensor

typedef short bf16x8 __attribute__((ext_vector_type(8)));
typedef float f32x4 __attribute__((ext_vector_type(4)));

// Split fp32 -> bf16 hi + bf16 lo (truncation is fine: only the dropped lo*lo
// term matters, ~2^-17 relative -> z-error ~1e-3 absolute, threshold is 2e-2).
__device__ __forceinline__ void split8(const float* v, bf16x8& h, bf16x8& l) {
#pragma unroll
  for (int j = 0; j < 8; ++j) {
    unsigned u = __float_as_uint(v[j]);
    unsigned short hb = (unsigned short)(u >> 16);
    float hf = __uint_as_float(((unsigned)hb) << 16);
    float rest = v[j] - hf;
    h[j] = (short)hb;
    l[j] = (short)(__float_as_uint(rest) >> 16);
  }
}

// C[n][mt] = W[n][k] @ S[k][mt] (+ bias[n]), n=512, k=512, mt=65536.
// Split-bf16 MFMA (hh+hl+lh). Grid: (256 mt-groups, 8 n-groups), 256 threads.
__global__ __launch_bounds__(256, 1) void wgemm(
    const float* __restrict__ W, const float* __restrict__ S,
    const float* __restrict__ bias, float* __restrict__ C) {
  const int tid = threadIdx.x;
  const int wv = tid >> 6;
  const int L = tid & 63;
  const int lo16 = L & 15;
  const int kq = L >> 4;
  const int n0 = blockIdx.y * 64;
  const int mt0 = blockIdx.x * 256 + wv * 64;

  f32x4 acc[4][4];
#pragma unroll
  for (int i = 0; i < 4; ++i)
#pragma unroll
    for (int j = 0; j < 4; ++j) acc[i][j] = (f32x4)0.0f;

  for (int kb = 0; kb < NXX; kb += 32) {
    const int ka = kb + kq * 8;
    bf16x8 Ah[4], Al[4], Bh[4], Bl[4];
#pragma unroll
    for (int i = 0; i < 4; ++i) {
      const float* p = W + (size_t)(n0 + i * 16 + lo16) * NXX + ka;
      float4 q0 = ((const float4*)p)[0];
      float4 q1 = ((const float4*)p)[1];
      float v[8] = {q0.x, q0.y, q0.z, q0.w, q1.x, q1.y, q1.z, q1.w};
      split8(v, Ah[i], Al[i]);
    }
#pragma unroll
    for (int j = 0; j < 4; ++j) {
      const int mt = mt0 + j * 16 + lo16;
      float v[8];
#pragma unroll
      for (int jj = 0; jj < 8; ++jj) v[jj] = S[(size_t)(ka + jj) * MT + mt];
      split8(v, Bh[j], Bl[j]);
    }
#pragma unroll
    for (int i = 0; i < 4; ++i)
#pragma unroll
      for (int j = 0; j < 4; ++j) {
        acc[i][j] = __builtin_amdgcn_mfma_f32_16x16x32_bf16(Ah[i], Bh[j], acc[i][j], 0, 0, 0);
        acc[i][j] = __builtin_amdgcn_mfma_f32_16x16x32_bf16(Ah[i], Bl[j], acc[i][j], 0, 0, 0);
        acc[i][j] = __builtin_amdgcn_mfma_f32_16x16x32_bf16(Al[i], Bh[j], acc[i][j], 0, 0, 0);
      }
  }
  // D layout: col = lane&15 (mt), row = (lane>>4)*4 + reg.
#pragma unroll
  for (int i = 0; i < 4; ++i) {
    const int nb = n0 + i * 16 + kq * 4;
#pragma unroll
    for (int r = 0; r < 4; ++r) {
      const float bv = bias ? bias[nb + r] : 0.0f;
#pragma unroll
      for (int j = 0; j < 4; ++j) {
        const int mt = mt0 + j * 16 + lo16;
        C[(size_t)(nb + r) * MT + mt] = acc[i][j][r] + bv;
      }
    }
  }
}

// Persistent cooperative scan: 32 WGs = 8 row-groups (64 rows) x 4 m-groups (16 cols).
// Waa slice lives in registers as split-bf16 A-fragments (4 waves split K 128 each).
// a_{t-1} exchanged via compact ping-pong in ws with agent-scope relaxed atomics.
__global__ __launch_bounds__(256, 1) void scan_kernel(
    const float* __restrict__ Waa, const float* __restrict__ a0,
    float* __restrict__ AZ, float* __restrict__ pp, unsigned* __restrict__ bar) {
  const int tid = threadIdx.x;
  const int wv = tid >> 6;
  const int L = tid & 63;
  const int lo16 = L & 15;
  const int kq = L >> 4;
  const int wg = blockIdx.x;
  const int rg = wg >> 2;
  const int mg = wg & 3;
  const int n0 = rg * 64;
  const int m0 = mg * 16;
  const int kw = wv * 128;

  // A-fragments of Waa: [rowtile 0..3][kstep 0..3], hi+lo. 128 VGPRs, persistent.
  bf16x8 Ah[4][4], Al[4][4];
#pragma unroll
  for (int i = 0; i < 4; ++i)
#pragma unroll
    for (int s = 0; s < 4; ++s) {
      const float* p = Waa + (size_t)(n0 + i * 16 + lo16) * NA + kw + s * 32 + kq * 8;
      float4 q0 = ((const float4*)p)[0];
      float4 q1 = ((const float4*)p)[1];
      float v[8] = {q0.x, q0.y, q0.z, q0.w, q1.x, q1.y, q1.z, q1.w};
      split8(v, Ah[i][s], Al[i][s]);
    }

  __shared__ float red[4 * 64 * 17];  // [wave][row 64][m 16 pad 17]

  const int rr = tid >> 2;  // output row within slice
  const int mq = tid & 3;   // output m-quad
  const size_t zb = ((size_t)(n0 + rr) * MBATCH + (m0 + mq * 4)) * TSTEPS;

  unsigned* cnt = bar;
  unsigned* ep = bar + 64;  // separate cacheline

  for (int t = 0; t < TSTEPS; ++t) {
    // Prefetch this step's Z slice early (only this WG ever touches it).
    float zv[4];
#pragma unroll
    for (int jj = 0; jj < 4; ++jj) zv[jj] = AZ[zb + (size_t)jj * TSTEPS + t];

    // B-fragments of a_{t-1} (coherent reads; a0 has identical [n][m] layout).
    float* ap = (float*)((t == 0) ? a0 : (pp + ((t & 1) ^ 1) * (NA * MBATCH)));
    bf16x8 Bh[4], Bl[4];
#pragma unroll
    for (int s = 0; s < 4; ++s) {
      const int k = kw + s * 32 + kq * 8;
      float v[8];
#pragma unroll
      for (int j = 0; j < 8; ++j)
        v[j] = __hip_atomic_load(ap + (size_t)(k + j) * MBATCH + m0 + lo16,
                                 __ATOMIC_RELAXED, __HIP_MEMORY_SCOPE_AGENT);
      split8(v, Bh[s], Bl[s]);
    }

    f32x4 acc[4];
#pragma unroll
    for (int i = 0; i < 4; ++i) acc[i] = (f32x4)0.0f;
#pragma unroll
    for (int i = 0; i < 4; ++i)
#pragma unroll
      for (int s = 0; s < 4; ++s) {
        acc[i] = __builtin_amdgcn_mfma_f32_16x16x32_bf16(Ah[i][s], Bh[s], acc[i], 0, 0, 0);
        acc[i] = __builtin_amdgcn_mfma_f32_16x16x32_bf16(Ah[i][s], Bl[s], acc[i], 0, 0, 0);
        acc[i] = __builtin_amdgcn_mfma_f32_16x16x32_bf16(Al[i][s], Bh[s], acc[i], 0, 0, 0);
      }

    // K-partial reduction across the 4 waves through LDS.
#pragma unroll
    for (int i = 0; i < 4; ++i)
#pragma unroll
      for (int r = 0; r < 4; ++r)
        red[(wv * 64 + i * 16 + kq * 4 + r) * 17 + lo16] = acc[i][r];
    __syncthreads();

#pragma unroll
    for (int jj = 0; jj < 4; ++jj) {
      const int m = mq * 4 + jj;
      float z = zv[jj];
#pragma unroll
      for (int w = 0; w < 4; ++w) z += red[(w * 64 + rr) * 17 + m];
      const float e = __expf(z + z);          // e^{2z}; inf/0 saturate correctly
      const float a = 1.0f - 2.0f / (e + 1.0f);
      AZ[zb + (size_t)jj * TSTEPS + t] = a;   // strided final output (L2-combined)
      __hip_atomic_store(pp + (t & 1) * (NA * MBATCH) + (size_t)(n0 + rr) * MBATCH + m0 + m,
                         a, __ATOMIC_RELAXED, __HIP_MEMORY_SCOPE_AGENT);
    }

    // Device-wide epoch barrier (32 arrivals).
    __syncthreads();
    if (tid == 0) {
      unsigned p = __hip_atomic_fetch_add(cnt, 1u, __ATOMIC_ACQ_REL, __HIP_MEMORY_SCOPE_AGENT);
      if (p == 31u) {
        __hip_atomic_store(cnt, 0u, __ATOMIC_RELAXED, __HIP_MEMORY_SCOPE_AGENT);
        __hip_atomic_store(ep, (unsigned)(t + 1), __ATOMIC_RELEASE, __HIP_MEMORY_SCOPE_AGENT);
      } else {
        while (__hip_atomic_load(ep, __ATOMIC_ACQUIRE, __HIP_MEMORY_SCOPE_AGENT) < (unsigned)(t + 1))
          __builtin_amdgcn_s_sleep(1);
      }
    }
    __syncthreads();
  }
}

// Softmax over the batch axis m for each (n,t). One thread per (n,t), 64 values
// in registers; lanes are consecutive t -> every m-load is coalesced.
__global__ __launch_bounds__(256, 2) void softmax_m(float* __restrict__ Y) {
  const int idx = blockIdx.x * 256 + threadIdx.x;
  const int n = idx >> 10;
  const int t = idx & 1023;
  float* base = Y + (size_t)n * MT + t;
  float v[64];
  float mx = -3.0e38f;
#pragma unroll
  for (int m = 0; m < 64; ++m) {
    v[m] = base[(size_t)m * TSTEPS];
    mx = fmaxf(mx, v[m]);
  }
  float s = 0.0f;
#pragma unroll
  for (int m = 0; m < 64; ++m) {
    v[m] = __expf(v[m] - mx);
    s += v[m];
  }
  const float inv = 1.0f / s;
#pragma unroll
  for (int m = 0; m < 64; ++m) base[(size_t)m * TSTEPS] = v[m] * inv;
}

extern "C" void kernel_launch(void* const* d_in, const int* in_sizes, int n_in,
                              void* d_out, int out_size, void* d_ws, size_t ws_size,
                              hipStream_t stream) {
  const float* x   = (const float*)d_in[0];
  const float* a0  = (const float*)d_in[1];
  const float* Waa = (const float*)d_in[2];
  const float* Wax = (const float*)d_in[3];
  const float* Wya = (const float*)d_in[4];
  const float* ba  = (const float*)d_in[5];
  // by (d_in[6]) is a constant shift along the softmax axis -> cancels exactly.

  float* A = (float*)d_out;       // a_next region, [n][m][t]; holds Z pre-scan
  float* Y = A + (size_t)ASZ;     // y_pred region, [n][m][t]

  unsigned* bar = (unsigned*)d_ws;               // barrier counters (1 KB)
  float* pp = (float*)((char*)d_ws + 1024);      // ping-pong a buffers, 2 x 128 KB

  hipMemsetAsync(d_ws, 0, 1024, stream);

  // Phase 1: Z = Wax @ X + ba  (in-place into the a-region of d_out)
  wgemm<<<dim3(256, 8), 256, 0, stream>>>(Wax, x, ba, A);

  // Phase 2: recurrence a_t = tanh(Waa@a_{t-1} + Z_t), overwrites Z with a.
  {
    void* args[] = {(void*)&Waa, (void*)&a0, (void*)&A, (void*)&pp, (void*)&bar};
    hipLaunchCooperativeKernel((const void*)scan_kernel, dim3(32), dim3(256), args, 0, stream);
  }

  // Phase 3: logits = Wya @ A  (by omitted: softmax shift-invariant)
  wgemm<<<dim3(256, 8), 256, 0, stream>>>(Wya, A, (const float*)nullptr, Y);

  // Phase 4: softmax over batch axis, in place.
  softmax_m<<<2048, 256, 0, stream>>>(Y);
}

// Round 2
// 5986.753 us; speedup vs baseline: 1.3281x; 1.3281x over previous
//
#include <hip/hip_runtime.h>

#define NA 512
#define NXX 512
#define MBATCH 64
#define TSTEPS 1024
#define MT (MBATCH * TSTEPS)       // 65536 flattened (m,t)
#define ASZ (NA * MBATCH * TSTEPS) // 33554432 elements per output tensor
#define PPC (NA * 16)              // per-chain ping-pong slice (floats)

typedef short bf16x8 __attribute__((ext_vector_type(8)));
typedef float f32x4 __attribute__((ext_vector_type(4)));

// Split fp32 -> bf16 hi + bf16 lo (3-term MFMA keeps error ~1e-3 << 2e-2).
__device__ __forceinline__ void split8(const float* v, bf16x8& h, bf16x8& l) {
#pragma unroll
  for (int j = 0; j < 8; ++j) {
    unsigned u = __float_as_uint(v[j]);
    unsigned short hb = (unsigned short)(u >> 16);
    float hf = __uint_as_float(((unsigned)hb) << 16);
    float rest = v[j] - hf;
    h[j] = (short)hb;
    l[j] = (short)(__float_as_uint(rest) >> 16);
  }
}

// C[n][mt] = W[n][k] @ S[k][mt] (+ bias[n]), n=512, k=512, mt=65536.
__global__ __launch_bounds__(256, 1) void wgemm(
    const float* __restrict__ W, const float* __restrict__ S,
    const float* __restrict__ bias, float* __restrict__ C) {
  const int tid = threadIdx.x;
  const int wv = tid >> 6;
  const int L = tid & 63;
  const int lo16 = L & 15;
  const int kq = L >> 4;
  const int n0 = blockIdx.y * 64;
  const int mt0 = blockIdx.x * 256 + wv * 64;

  f32x4 acc[4][4];
#pragma unroll
  for (int i = 0; i < 4; ++i)
#pragma unroll
    for (int j = 0; j < 4; ++j) acc[i][j] = (f32x4)0.0f;

  for (int kb = 0; kb < NXX; kb += 32) {
    const int ka = kb + kq * 8;
    bf16x8 Ah[4], Al[4], Bh[4], Bl[4];
#pragma unroll
    for (int i = 0; i < 4; ++i) {
      const float* p = W + (size_t)(n0 + i * 16 + lo16) * NXX + ka;
      float4 q0 = ((const float4*)p)[0];
      float4 q1 = ((const float4*)p)[1];
      float v[8] = {q0.x, q0.y, q0.z, q0.w, q1.x, q1.y, q1.z, q1.w};
      split8(v, Ah[i], Al[i]);
    }
#pragma unroll
    for (int j = 0; j < 4; ++j) {
      const int mt = mt0 + j * 16 + lo16;
      float v[8];
#pragma unroll
      for (int jj = 0; jj < 8; ++jj) v[jj] = S[(size_t)(ka + jj) * MT + mt];
      split8(v, Bh[j], Bl[j]);
    }
#pragma unroll
    for (int i = 0; i < 4; ++i)
#pragma unroll
      for (int j = 0; j < 4; ++j) {
        acc[i][j] = __builtin_amdgcn_mfma_f32_16x16x32_bf16(Ah[i], Bh[j], acc[i][j], 0, 0, 0);
        acc[i][j] = __builtin_amdgcn_mfma_f32_16x16x32_bf16(Ah[i], Bl[j], acc[i][j], 0, 0, 0);
        acc[i][j] = __builtin_amdgcn_mfma_f32_16x16x32_bf16(Al[i], Bh[j], acc[i][j], 0, 0, 0);
      }
  }
#pragma unroll
  for (int i = 0; i < 4; ++i) {
    const int nb = n0 + i * 16 + kq * 4;
#pragma unroll
    for (int r = 0; r < 4; ++r) {
      const float bv = bias ? bias[nb + r] : 0.0f;
#pragma unroll
      for (int j = 0; j < 4; ++j) {
        const int mt = mt0 + j * 16 + lo16;
        C[(size_t)(nb + r) * MT + mt] = acc[i][j][r] + bv;
      }
    }
  }
}

// Persistent scan. 32 WGs = 4 independent chains (m-groups of 16 cols) x 8
// row-groups. Chain-local 8-flag epoch barrier (no RMW). a exchanged through
// compact per-chain [k][16] ping-pong slices in ws via sc1 (agent) atomics.
// Z (input) is read-only; final a-output stores happen AFTER the flag store
// so they stay off the inter-step critical path.
__global__ __launch_bounds__(256, 1) void scan_kernel(
    const float* __restrict__ Waa, const float* __restrict__ a0,
    const float* __restrict__ Z, float* __restrict__ Aout,
    float* __restrict__ pp, unsigned* __restrict__ flags) {
  const int tid = threadIdx.x;
  const int wv = tid >> 6;
  const int L = tid & 63;
  const int lo16 = L & 15;
  const int kq = L >> 4;
  const int wg = blockIdx.x;
  const int rg = wg >> 2;  // row-group within chain (8)
  const int mg = wg & 3;   // chain id
  const int n0 = rg * 64;
  const int m0 = mg * 16;
  const int kw = wv * 128;

  // Persistent split-bf16 A-fragments of the Waa slice (unified VGPR/AGPR file).
  bf16x8 Ah[4][4], Al[4][4];
#pragma unroll
  for (int i = 0; i < 4; ++i)
#pragma unroll
    for (int s = 0; s < 4; ++s) {
      const float* p = Waa + (size_t)(n0 + i * 16 + lo16) * NA + kw + s * 32 + kq * 8;
      float4 q0 = ((const float4*)p)[0];
      float4 q1 = ((const float4*)p)[1];
      float v[8] = {q0.x, q0.y, q0.z, q0.w, q1.x, q1.y, q1.z, q1.w};
      split8(v, Ah[i][s], Al[i][s]);
    }

  __shared__ float red[2][4 * 64 * 17];  // double-buffered K-reduction

  const int rr = tid >> 2;  // output row within 64-row slice
  const int mq = tid & 3;   // m-quad
  const size_t zb = ((size_t)(n0 + rr) * MBATCH + (m0 + mq * 4)) * TSTEPS;

  float* ppA = pp + (size_t)mg * PPC;            // buffer 0 slice
  float* ppB = pp + 4 * PPC + (size_t)mg * PPC;  // buffer 1 slice

  unsigned* pollf = flags + (size_t)(mg * 8 + (L & 7)) * 16;  // 64B-strided slots
  unsigned* myf = flags + (size_t)(mg * 8 + rg) * 16;

  float zv[4];
#pragma unroll
  for (int jj = 0; jj < 4; ++jj) zv[jj] = Z[zb + (size_t)jj * TSTEPS];

  for (int t = 0; t < TSTEPS; ++t) {
    if (t) {
      // Wait until every row-group in this chain finished step t-1.
      while (__hip_atomic_load(pollf, __ATOMIC_RELAXED, __HIP_MEMORY_SCOPE_AGENT) <
             (unsigned)t) {}
      __builtin_amdgcn_fence(__ATOMIC_ACQUIRE, "agent");
    }

    // B-fragments of a_{t-1}.
    const float* ap = (t == 0) ? a0 : ((t & 1) ? ppA : ppB);
    const int kst = (t == 0) ? MBATCH : 16;
    const int cof = (t == 0) ? (m0 + lo16) : lo16;
    bf16x8 Bh[4], Bl[4];
#pragma unroll
    for (int s = 0; s < 4; ++s) {
      const int k = kw + s * 32 + kq * 8;
      float v[8];
#pragma unroll
      for (int j = 0; j < 8; ++j)
        v[j] = __hip_atomic_load((const float*)(ap + (size_t)(k + j) * kst + cof),
                                 __ATOMIC_RELAXED, __HIP_MEMORY_SCOPE_AGENT);
      split8(v, Bh[s], Bl[s]);
    }

    f32x4 acc[4];
#pragma unroll
    for (int i = 0; i < 4; ++i) acc[i] = (f32x4)0.0f;
#pragma unroll
    for (int i = 0; i < 4; ++i)
#pragma unroll
      for (int s = 0; s < 4; ++s) {
        acc[i] = __builtin_amdgcn_mfma_f32_16x16x32_bf16(Ah[i][s], Bh[s], acc[i], 0, 0, 0);
        acc[i] = __builtin_amdgcn_mfma_f32_16x16x32_bf16(Ah[i][s], Bl[s], acc[i], 0, 0, 0);
        acc[i] = __builtin_amdgcn_mfma_f32_16x16x32_bf16(Al[i][s], Bh[s], acc[i], 0, 0, 0);
      }

    // Cross-wave K reduction (double-buffered; one barrier between wr/rd).
    float* rb = red[t & 1];
#pragma unroll
    for (int i = 0; i < 4; ++i)
#pragma unroll
      for (int r = 0; r < 4; ++r)
        rb[(wv * 64 + i * 16 + kq * 4 + r) * 17 + lo16] = acc[i][r];
    __syncthreads();

    float av[4];
#pragma unroll
    for (int jj = 0; jj < 4; ++jj) {
      const int m = mq * 4 + jj;
      float z = zv[jj];
#pragma unroll
      for (int w = 0; w < 4; ++w) z += rb[(w * 64 + rr) * 17 + m];
      const float e = __expf(z + z);  // e^{2z}; saturates correctly at +/-inf
      av[jj] = 1.0f - 2.0f / (e + 1.0f);
    }

    // Publish a_t for the chain: compact coalesced sc1 stores.
    float* wb = (t & 1) ? ppB : ppA;
#pragma unroll
    for (int jj = 0; jj < 4; ++jj)
      __hip_atomic_store(wb + (size_t)(n0 + rr) * 16 + mq * 4 + jj, av[jj],
                         __ATOMIC_RELAXED, __HIP_MEMORY_SCOPE_AGENT);
    __syncthreads();  // vmcnt(0) drain: all waves' pp stores complete
    if (tid == 0) {
      __builtin_amdgcn_fence(__ATOMIC_RELEASE, "agent");
      __hip_atomic_store(myf, (unsigned)(t + 1), __ATOMIC_RELAXED,
                         __HIP_MEMORY_SCOPE_AGENT);
    }

    // Off-critical-path: final strided output store + next-step Z prefetch
    // (in flight during the next poll).
#pragma unroll
    for (int jj = 0; jj < 4; ++jj)
      __hip_atomic_store(Aout + zb + (size_t)jj * TSTEPS + t, av[jj],
                         __ATOMIC_RELAXED, __HIP_MEMORY_SCOPE_AGENT);
    if (t + 1 < TSTEPS) {
#pragma unroll
      for (int jj = 0; jj < 4; ++jj) zv[jj] = Z[zb + (size_t)jj * TSTEPS + t + 1];
    }
  }
}

// Softmax over the batch axis m for each (n,t), in place.
__global__ __launch_bounds__(256, 2) void softmax_m(float* __restrict__ Y) {
  const int idx = blockIdx.x * 256 + threadIdx.x;
  const int n = idx >> 10;
  const int t = idx & 1023;
  float* base = Y + (size_t)n * MT + t;
  float v[64];
  float mx = -3.0e38f;
#pragma unroll
  for (int m = 0; m < 64; ++m) {
    v[m] = base[(size_t)m * TSTEPS];
    mx = fmaxf(mx, v[m]);
  }
  float s = 0.0f;
#pragma unroll
  for (int m = 0; m < 64; ++m) {
    v[m] = __expf(v[m] - mx);
    s += v[m];
  }
  const float inv = 1.0f / s;
#pragma unroll
  for (int m = 0; m < 64; ++m) base[(size_t)m * TSTEPS] = v[m] * inv;
}

extern "C" void kernel_launch(void* const* d_in, const int* in_sizes, int n_in,
                              void* d_out, int out_size, void* d_ws, size_t ws_size,
                              hipStream_t stream) {
  const float* x   = (const float*)d_in[0];
  const float* a0  = (const float*)d_in[1];
  const float* Waa = (const float*)d_in[2];
  const float* Wax = (const float*)d_in[3];
  const float* Wya = (const float*)d_in[4];
  const float* ba  = (const float*)d_in[5];
  // by (d_in[6]) cancels under softmax over the batch axis.

  float* A = (float*)d_out;    // final a_next [n][m][t]
  float* Y = A + (size_t)ASZ;  // staging for Z, then logits/y [n][m][t]

  unsigned* flags = (unsigned*)d_ws;          // 32 x 64B epoch slots
  float* pp = (float*)((char*)d_ws + 4096);   // 2 x 4 x PPC floats (256 KB)

  hipMemsetAsync(d_ws, 0, 4096, stream);

  // Phase 1: Z = Wax @ X + ba  -> Y region (read-only input for the scan)
  wgemm<<<dim3(256, 8), 256, 0, stream>>>(Wax, x, ba, Y);

  // Phase 2: a_t = tanh(Waa@a_{t-1} + Z_t) -> A region
  {
    void* args[] = {(void*)&Waa, (void*)&a0, (void*)&Y, (void*)&A,
                    (void*)&pp, (void*)&flags};
    hipLaunchCooperativeKernel((const void*)scan_kernel, dim3(32), dim3(256),
                               args, 0, stream);
  }

  // Phase 3: logits = Wya @ A -> Y region (overwrites Z, which is dead)
  wgemm<<<dim3(256, 8), 256, 0, stream>>>(Wya, A, (const float*)nullptr, Y);

  // Phase 4: softmax over batch axis, in place.
  softmax_m<<<2048, 256, 0, stream>>>(Y);
}

// Round 5
// 4982.225 us; speedup vs baseline: 1.5959x; 1.2016x over previous
//
#include <hip/hip_runtime.h>

#define NA 512
#define NXX 512
#define MBATCH 64
#define TSTEPS 1024
#define MT (MBATCH * TSTEPS)       // 65536 flattened (m,t)
#define ASZ (NA * MBATCH * TSTEPS) // 33554432 elements per output tensor
#define PPC (NA * 16)              // per-chain ping-pong slice (floats)

typedef short bf16x8 __attribute__((ext_vector_type(8)));
typedef float f32x4 __attribute__((ext_vector_type(4)));

// Split fp32 -> bf16 hi + bf16 lo (3-term MFMA keeps error ~1e-3 << 2e-2).
__device__ __forceinline__ void split8(const float* v, bf16x8& h, bf16x8& l) {
#pragma unroll
  for (int j = 0; j < 8; ++j) {
    unsigned u = __float_as_uint(v[j]);
    unsigned short hb = (unsigned short)(u >> 16);
    float hf = __uint_as_float(((unsigned)hb) << 16);
    float rest = v[j] - hf;
    h[j] = (short)hb;
    l[j] = (short)(__float_as_uint(rest) >> 16);
  }
}

// C[n][mt] = W[n][k] @ S[k][mt] (+ bias[n]), n=512, k=512, mt=65536.
__global__ __launch_bounds__(256, 1) void wgemm(
    const float* __restrict__ W, const float* __restrict__ S,
    const float* __restrict__ bias, float* __restrict__ C) {
  const int tid = threadIdx.x;
  const int wv = tid >> 6;
  const int L = tid & 63;
  const int lo16 = L & 15;
  const int kq = L >> 4;
  const int n0 = blockIdx.y * 64;
  const int mt0 = blockIdx.x * 256 + wv * 64;

  f32x4 acc[4][4];
#pragma unroll
  for (int i = 0; i < 4; ++i)
#pragma unroll
    for (int j = 0; j < 4; ++j) acc[i][j] = (f32x4)0.0f;

  for (int kb = 0; kb < NXX; kb += 32) {
    const int ka = kb + kq * 8;
    bf16x8 Ah[4], Al[4], Bh[4], Bl[4];
#pragma unroll
    for (int i = 0; i < 4; ++i) {
      const float* p = W + (size_t)(n0 + i * 16 + lo16) * NXX + ka;
      float4 q0 = ((const float4*)p)[0];
      float4 q1 = ((const float4*)p)[1];
      float v[8] = {q0.x, q0.y, q0.z, q0.w, q1.x, q1.y, q1.z, q1.w};
      split8(v, Ah[i], Al[i]);
    }
#pragma unroll
    for (int j = 0; j < 4; ++j) {
      const int mt = mt0 + j * 16 + lo16;
      float v[8];
#pragma unroll
      for (int jj = 0; jj < 8; ++jj) v[jj] = S[(size_t)(ka + jj) * MT + mt];
      split8(v, Bh[j], Bl[j]);
    }
#pragma unroll
    for (int i = 0; i < 4; ++i)
#pragma unroll
      for (int j = 0; j < 4; ++j) {
        acc[i][j] = __builtin_amdgcn_mfma_f32_16x16x32_bf16(Ah[i], Bh[j], acc[i][j], 0, 0, 0);
        acc[i][j] = __builtin_amdgcn_mfma_f32_16x16x32_bf16(Ah[i], Bl[j], acc[i][j], 0, 0, 0);
        acc[i][j] = __builtin_amdgcn_mfma_f32_16x16x32_bf16(Al[i], Bh[j], acc[i][j], 0, 0, 0);
      }
  }
#pragma unroll
  for (int i = 0; i < 4; ++i) {
    const int nb = n0 + i * 16 + kq * 4;
#pragma unroll
    for (int r = 0; r < 4; ++r) {
      const float bv = bias ? bias[nb + r] : 0.0f;
#pragma unroll
      for (int j = 0; j < 4; ++j) {
        const int mt = mt0 + j * 16 + lo16;
        C[(size_t)(nb + r) * MT + mt] = acc[i][j][r] + bv;
      }
    }
  }
}

// Persistent scan. 32 WGs = 4 independent chains (m-groups of 16 cols) x 8
// row-groups. Chain-local 8-flag epoch barrier (no RMW). a exchanged through
// compact per-chain [k][16] ping-pong slices in ws via sc1 (agent) atomics.
// Visibility: pp stores are sc1 write-through; the publish __syncthreads
// drains each wave's vmcnt(0), so all pp data is LLC-acked before tid0's
// relaxed flag store. (R2 additionally had a release fence here — its only
// ISA effect was a per-step buffer_wbl2 L2 writeback; removed this round.)
// Aout uses PLAIN cached stores: only the next kernel launch reads it, so the
// 4KB-strided 4B writes accumulate into fully-dirty L2 lines over 16 steps
// and write back lazily instead of write-through per step.
__global__ __launch_bounds__(256, 1) void scan_kernel(
    const float* __restrict__ Waa, const float* __restrict__ a0,
    const float* __restrict__ Z, float* __restrict__ Aout,
    float* __restrict__ pp, unsigned* __restrict__ flags) {
  const int tid = threadIdx.x;
  const int wv = tid >> 6;
  const int L = tid & 63;
  const int lo16 = L & 15;
  const int kq = L >> 4;
  const int wg = blockIdx.x;
  const int rg = wg >> 2;  // row-group within chain (8)
  const int mg = wg & 3;   // chain id
  const int n0 = rg * 64;
  const int m0 = mg * 16;
  const int kw = wv * 128;

  // Persistent split-bf16 A-fragments of the Waa slice.
  bf16x8 Ah[4][4], Al[4][4];
#pragma unroll
  for (int i = 0; i < 4; ++i)
#pragma unroll
    for (int s = 0; s < 4; ++s) {
      const float* p = Waa + (size_t)(n0 + i * 16 + lo16) * NA + kw + s * 32 + kq * 8;
      float4 q0 = ((const float4*)p)[0];
      float4 q1 = ((const float4*)p)[1];
      float v[8] = {q0.x, q0.y, q0.z, q0.w, q1.x, q1.y, q1.z, q1.w};
      split8(v, Ah[i][s], Al[i][s]);
    }

  __shared__ float red[2][4 * 64 * 17];  // double-buffered K-reduction

  const int rr = tid >> 2;  // output row within 64-row slice
  const int mq = tid & 3;   // m-quad
  const size_t zb = ((size_t)(n0 + rr) * MBATCH + (m0 + mq * 4)) * TSTEPS;

  float* ppA = pp + (size_t)mg * PPC;            // buffer 0 slice
  float* ppB = pp + 4 * PPC + (size_t)mg * PPC;  // buffer 1 slice

  unsigned* pollf = flags + (size_t)(mg * 8 + (L & 7)) * 16;  // 64B-strided slots
  unsigned* myf = flags + (size_t)(mg * 8 + rg) * 16;

  float zv[4];
#pragma unroll
  for (int jj = 0; jj < 4; ++jj) zv[jj] = Z[zb + (size_t)jj * TSTEPS];

  for (int t = 0; t < TSTEPS; ++t) {
    if (t) {
      // Wait until every row-group in this chain finished step t-1.
      while (__hip_atomic_load(pollf, __ATOMIC_RELAXED, __HIP_MEMORY_SCOPE_AGENT) <
             (unsigned)t) {}
      __builtin_amdgcn_fence(__ATOMIC_ACQUIRE, "agent");
    }

    // B-fragments of a_{t-1}.
    const float* ap = (t == 0) ? a0 : ((t & 1) ? ppA : ppB);
    const int kst = (t == 0) ? MBATCH : 16;
    const int cof = (t == 0) ? (m0 + lo16) : lo16;
    bf16x8 Bh[4], Bl[4];
#pragma unroll
    for (int s = 0; s < 4; ++s) {
      const int k = kw + s * 32 + kq * 8;
      float v[8];
#pragma unroll
      for (int j = 0; j < 8; ++j)
        v[j] = __hip_atomic_load((const float*)(ap + (size_t)(k + j) * kst + cof),
                                 __ATOMIC_RELAXED, __HIP_MEMORY_SCOPE_AGENT);
      split8(v, Bh[s], Bl[s]);
    }

    f32x4 acc[4];
#pragma unroll
    for (int i = 0; i < 4; ++i) acc[i] = (f32x4)0.0f;
#pragma unroll
    for (int i = 0; i < 4; ++i)
#pragma unroll
      for (int s = 0; s < 4; ++s) {
        acc[i] = __builtin_amdgcn_mfma_f32_16x16x32_bf16(Ah[i][s], Bh[s], acc[i], 0, 0, 0);
        acc[i] = __builtin_amdgcn_mfma_f32_16x16x32_bf16(Ah[i][s], Bl[s], acc[i], 0, 0, 0);
        acc[i] = __builtin_amdgcn_mfma_f32_16x16x32_bf16(Al[i][s], Bh[s], acc[i], 0, 0, 0);
      }

    // Cross-wave K reduction (double-buffered; one barrier between wr/rd).
    float* rb = red[t & 1];
#pragma unroll
    for (int i = 0; i < 4; ++i)
#pragma unroll
      for (int r = 0; r < 4; ++r)
        rb[(wv * 64 + i * 16 + kq * 4 + r) * 17 + lo16] = acc[i][r];
    __syncthreads();

    float av[4];
#pragma unroll
    for (int jj = 0; jj < 4; ++jj) {
      const int m = mq * 4 + jj;
      float z = zv[jj];
#pragma unroll
      for (int w = 0; w < 4; ++w) z += rb[(w * 64 + rr) * 17 + m];
      const float e = __expf(z + z);  // e^{2z}; saturates correctly at +/-inf
      av[jj] = 1.0f - 2.0f / (e + 1.0f);
    }

    // Publish a_t for the chain: compact coalesced sc1 stores.
    float* wb = (t & 1) ? ppB : ppA;
#pragma unroll
    for (int jj = 0; jj < 4; ++jj)
      __hip_atomic_store(wb + (size_t)(n0 + rr) * 16 + mq * 4 + jj, av[jj],
                         __ATOMIC_RELAXED, __HIP_MEMORY_SCOPE_AGENT);
    __syncthreads();  // vmcnt(0) drain per wave: all pp stores are LLC-acked
    if (tid == 0) {
      __hip_atomic_store(myf, (unsigned)(t + 1), __ATOMIC_RELAXED,
                         __HIP_MEMORY_SCOPE_AGENT);
    }

    // Off-critical-path: final strided output store (plain cached) + next-step
    // Z prefetch (in flight during the next poll).
#pragma unroll
    for (int jj = 0; jj < 4; ++jj)
      Aout[zb + (size_t)jj * TSTEPS + t] = av[jj];
    if (t + 1 < TSTEPS) {
#pragma unroll
      for (int jj = 0; jj < 4; ++jj) zv[jj] = Z[zb + (size_t)jj * TSTEPS + t + 1];
    }
  }
}

// Softmax over the batch axis m for each (n,t), in place.
__global__ __launch_bounds__(256, 2) void softmax_m(float* __restrict__ Y) {
  const int idx = blockIdx.x * 256 + threadIdx.x;
  const int n = idx >> 10;
  const int t = idx & 1023;
  float* base = Y + (size_t)n * MT + t;
  float v[64];
  float mx = -3.0e38f;
#pragma unroll
  for (int m = 0; m < 64; ++m) {
    v[m] = base[(size_t)m * TSTEPS];
    mx = fmaxf(mx, v[m]);
  }
  float s = 0.0f;
#pragma unroll
  for (int m = 0; m < 64; ++m) {
    v[m] = __expf(v[m] - mx);
    s += v[m];
  }
  const float inv = 1.0f / s;
#pragma unroll
  for (int m = 0; m < 64; ++m) base[(size_t)m * TSTEPS] = v[m] * inv;
}

extern "C" void kernel_launch(void* const* d_in, const int* in_sizes, int n_in,
                              void* d_out, int out_size, void* d_ws, size_t ws_size,
                              hipStream_t stream) {
  const float* x   = (const float*)d_in[0];
  const float* a0  = (const float*)d_in[1];
  const float* Waa = (const float*)d_in[2];
  const float* Wax = (const float*)d_in[3];
  const float* Wya = (const float*)d_in[4];
  const float* ba  = (const float*)d_in[5];
  // by (d_in[6]) cancels under softmax over the batch axis.

  float* A = (float*)d_out;    // final a_next [n][m][t]
  float* Y = A + (size_t)ASZ;  // staging for Z, then logits/y [n][m][t]

  unsigned* flags = (unsigned*)d_ws;          // 32 x 64B epoch slots
  float* pp = (float*)((char*)d_ws + 4096);   // 2 x 4 x PPC floats (256 KB)

  hipMemsetAsync(d_ws, 0, 4096, stream);

  // Phase 1: Z = Wax @ X + ba  -> Y region (read-only input for the scan)
  wgemm<<<dim3(256, 8), 256, 0, stream>>>(Wax, x, ba, Y);

  // Phase 2: a_t = tanh(Waa@a_{t-1} + Z_t) -> A region
  {
    void* args[] = {(void*)&Waa, (void*)&a0, (void*)&Y, (void*)&A,
                    (void*)&pp, (void*)&flags};
    hipLaunchCooperativeKernel((const void*)scan_kernel, dim3(32), dim3(256),
                               args, 0, stream);
  }

  // Phase 3: logits = Wya @ A -> Y region (overwrites Z, which is dead)
  wgemm<<<dim3(256, 8), 256, 0, stream>>>(Wya, A, (const float*)nullptr, Y);

  // Phase 4: softmax over batch axis, in place.
  softmax_m<<<2048, 256, 0, stream>>>(Y);
}

// Round 6
// 4477.493 us; speedup vs baseline: 1.7758x; 1.1127x over previous
//
#include <hip/hip_runtime.h>

#define NA 512
#define NXX 512
#define MBATCH 64
#define TSTEPS 1024
#define MT (MBATCH * TSTEPS)       // 65536 flattened (m,t)
#define ASZ (NA * MBATCH * TSTEPS) // 33554432 elements per output tensor
#define PPC (NA * 16)              // per-chain ping-pong slice (floats)

typedef short bf16x8 __attribute__((ext_vector_type(8)));
typedef float f32x4 __attribute__((ext_vector_type(4)));

// Split fp32 -> bf16 hi + bf16 lo (3-term MFMA keeps error ~1e-3 << 2e-2).
__device__ __forceinline__ void split8(const float* v, bf16x8& h, bf16x8& l) {
#pragma unroll
  for (int j = 0; j < 8; ++j) {
    unsigned u = __float_as_uint(v[j]);
    unsigned short hb = (unsigned short)(u >> 16);
    float hf = __uint_as_float(((unsigned)hb) << 16);
    float rest = v[j] - hf;
    h[j] = (short)hb;
    l[j] = (short)(__float_as_uint(rest) >> 16);
  }
}

// C[n][mt] = W[n][k] @ S[k][mt] (+ bias[n]), n=512, k=512, mt=65536.
__global__ __launch_bounds__(256, 1) void wgemm(
    const float* __restrict__ W, const float* __restrict__ S,
    const float* __restrict__ bias, float* __restrict__ C) {
  const int tid = threadIdx.x;
  const int wv = tid >> 6;
  const int L = tid & 63;
  const int lo16 = L & 15;
  const int kq = L >> 4;
  const int n0 = blockIdx.y * 64;
  const int mt0 = blockIdx.x * 256 + wv * 64;

  f32x4 acc[4][4];
#pragma unroll
  for (int i = 0; i < 4; ++i)
#pragma unroll
    for (int j = 0; j < 4; ++j) acc[i][j] = (f32x4)0.0f;

  for (int kb = 0; kb < NXX; kb += 32) {
    const int ka = kb + kq * 8;
    bf16x8 Ah[4], Al[4], Bh[4], Bl[4];
#pragma unroll
    for (int i = 0; i < 4; ++i) {
      const float* p = W + (size_t)(n0 + i * 16 + lo16) * NXX + ka;
      float4 q0 = ((const float4*)p)[0];
      float4 q1 = ((const float4*)p)[1];
      float v[8] = {q0.x, q0.y, q0.z, q0.w, q1.x, q1.y, q1.z, q1.w};
      split8(v, Ah[i], Al[i]);
    }
#pragma unroll
    for (int j = 0; j < 4; ++j) {
      const int mt = mt0 + j * 16 + lo16;
      float v[8];
#pragma unroll
      for (int jj = 0; jj < 8; ++jj) v[jj] = S[(size_t)(ka + jj) * MT + mt];
      split8(v, Bh[j], Bl[j]);
    }
#pragma unroll
    for (int i = 0; i < 4; ++i)
#pragma unroll
      for (int j = 0; j < 4; ++j) {
        acc[i][j] = __builtin_amdgcn_mfma_f32_16x16x32_bf16(Ah[i], Bh[j], acc[i][j], 0, 0, 0);
        acc[i][j] = __builtin_amdgcn_mfma_f32_16x16x32_bf16(Ah[i], Bl[j], acc[i][j], 0, 0, 0);
        acc[i][j] = __builtin_amdgcn_mfma_f32_16x16x32_bf16(Al[i], Bh[j], acc[i][j], 0, 0, 0);
      }
  }
#pragma unroll
  for (int i = 0; i < 4; ++i) {
    const int nb = n0 + i * 16 + kq * 4;
#pragma unroll
    for (int r = 0; r < 4; ++r) {
      const float bv = bias ? bias[nb + r] : 0.0f;
#pragma unroll
      for (int j = 0; j < 4; ++j) {
        const int mt = mt0 + j * 16 + lo16;
        C[(size_t)(nb + r) * MT + mt] = acc[i][j][r] + bv;
      }
    }
  }
}

// Persistent scan. 32 WGs = 4 independent chains (m-groups of 16 cols) x 8
// row-groups. Chain-local 8-flag epoch barrier (no RMW). a exchanged through
// compact per-chain [k][16] ping-pong slices in ws via sc1 (agent) atomics.
//
// SAFETY INVARIANT (why 2 slots suffice; cf. failed R3/R4): a WG's flag value
// t+1 certifies that WG finished its step-t READS (reads precede publish in
// program order, separated by __syncthreads). Every WG polls ALL 8 chain
// flags >= t before step t, so when anyone overwrites slot parity (t+1)&1
// (holding a_{t-1}), every reader of a_{t-1} has provably finished.
//
// Visibility: pp stores are sc1 write-through; the publish __syncthreads
// drains each wave's vmcnt(0), so all pp data is LLC-acked before tid0's
// relaxed flag store. Consumer-side: agent-scope relaxed atomic loads read
// the LLC directly (proven by the flag poll observing remote stores while
// spinning), so NO hardware acquire fence is needed — R5's per-step acquire
// lowered to an L2 invalidate that force-flushed partially-dirty Aout lines
// (2.8 GB WRITE_SIZE) and sat on the critical path. Only a compiler fence
// remains to pin the pp loads after the poll.
__global__ __launch_bounds__(256, 1) void scan_kernel(
    const float* __restrict__ Waa, const float* __restrict__ a0,
    const float* __restrict__ Z, float* __restrict__ Aout,
    float* __restrict__ pp, unsigned* __restrict__ flags) {
  const int tid = threadIdx.x;
  const int wv = tid >> 6;
  const int L = tid & 63;
  const int lo16 = L & 15;
  const int kq = L >> 4;
  const int wg = blockIdx.x;
  const int rg = wg >> 2;  // row-group within chain (8)
  const int mg = wg & 3;   // chain id
  const int n0 = rg * 64;
  const int m0 = mg * 16;
  const int kw = wv * 128;

  // Persistent split-bf16 A-fragments of the Waa slice.
  bf16x8 Ah[4][4], Al[4][4];
#pragma unroll
  for (int i = 0; i < 4; ++i)
#pragma unroll
    for (int s = 0; s < 4; ++s) {
      const float* p = Waa + (size_t)(n0 + i * 16 + lo16) * NA + kw + s * 32 + kq * 8;
      float4 q0 = ((const float4*)p)[0];
      float4 q1 = ((const float4*)p)[1];
      float v[8] = {q0.x, q0.y, q0.z, q0.w, q1.x, q1.y, q1.z, q1.w};
      split8(v, Ah[i][s], Al[i][s]);
    }

  __shared__ float red[2][4 * 64 * 17];  // double-buffered K-reduction

  const int rr = tid >> 2;  // output row within 64-row slice
  const int mq = tid & 3;   // m-quad
  const size_t zb = ((size_t)(n0 + rr) * MBATCH + (m0 + mq * 4)) * TSTEPS;

  float* ppA = pp + (size_t)mg * PPC;            // buffer 0 slice
  float* ppB = pp + 4 * PPC + (size_t)mg * PPC;  // buffer 1 slice

  unsigned* pollf = flags + (size_t)(mg * 8 + (L & 7)) * 16;  // 64B-strided slots
  unsigned* myf = flags + (size_t)(mg * 8 + rg) * 16;

  float zv[4];
#pragma unroll
  for (int jj = 0; jj < 4; ++jj) zv[jj] = Z[zb + (size_t)jj * TSTEPS];

  for (int t = 0; t < TSTEPS; ++t) {
    if (t) {
      // Wait until every row-group in this chain finished step t-1.
      while (__hip_atomic_load(pollf, __ATOMIC_RELAXED, __HIP_MEMORY_SCOPE_AGENT) <
             (unsigned)t) {}
      __atomic_signal_fence(__ATOMIC_ACQUIRE);  // compiler-only: pin loads below
    }

    // B-fragments of a_{t-1}.
    const float* ap = (t == 0) ? a0 : ((t & 1) ? ppA : ppB);
    const int kst = (t == 0) ? MBATCH : 16;
    const int cof = (t == 0) ? (m0 + lo16) : lo16;
    bf16x8 Bh[4], Bl[4];
#pragma unroll
    for (int s = 0; s < 4; ++s) {
      const int k = kw + s * 32 + kq * 8;
      float v[8];
#pragma unroll
      for (int j = 0; j < 8; ++j)
        v[j] = __hip_atomic_load((const float*)(ap + (size_t)(k + j) * kst + cof),
                                 __ATOMIC_RELAXED, __HIP_MEMORY_SCOPE_AGENT);
      split8(v, Bh[s], Bl[s]);
    }

    f32x4 acc[4];
#pragma unroll
    for (int i = 0; i < 4; ++i) acc[i] = (f32x4)0.0f;
#pragma unroll
    for (int i = 0; i < 4; ++i)
#pragma unroll
      for (int s = 0; s < 4; ++s) {
        acc[i] = __builtin_amdgcn_mfma_f32_16x16x32_bf16(Ah[i][s], Bh[s], acc[i], 0, 0, 0);
        acc[i] = __builtin_amdgcn_mfma_f32_16x16x32_bf16(Ah[i][s], Bl[s], acc[i], 0, 0, 0);
        acc[i] = __builtin_amdgcn_mfma_f32_16x16x32_bf16(Al[i][s], Bh[s], acc[i], 0, 0, 0);
      }

    // Cross-wave K reduction (double-buffered; one barrier between wr/rd).
    float* rb = red[t & 1];
#pragma unroll
    for (int i = 0; i < 4; ++i)
#pragma unroll
      for (int r = 0; r < 4; ++r)
        rb[(wv * 64 + i * 16 + kq * 4 + r) * 17 + lo16] = acc[i][r];
    __syncthreads();

    float av[4];
#pragma unroll
    for (int jj = 0; jj < 4; ++jj) {
      const int m = mq * 4 + jj;
      float z = zv[jj];
#pragma unroll
      for (int w = 0; w < 4; ++w) z += rb[(w * 64 + rr) * 17 + m];
      const float e = __expf(z + z);  // e^{2z}; saturates correctly at +/-inf
      av[jj] = 1.0f - 2.0f / (e + 1.0f);
    }

    // Publish a_t for the chain: compact coalesced sc1 stores.
    float* wb = (t & 1) ? ppB : ppA;
#pragma unroll
    for (int jj = 0; jj < 4; ++jj)
      __hip_atomic_store(wb + (size_t)(n0 + rr) * 16 + mq * 4 + jj, av[jj],
                         __ATOMIC_RELAXED, __HIP_MEMORY_SCOPE_AGENT);
    __syncthreads();  // vmcnt(0) drain per wave: all pp stores are LLC-acked
    if (tid == 0) {
      __hip_atomic_store(myf, (unsigned)(t + 1), __ATOMIC_RELAXED,
                         __HIP_MEMORY_SCOPE_AGENT);
    }

    // Off-critical-path: final strided output store (plain cached; lines fill
    // over 32 adjacent t's and write back lazily) + next-step Z prefetch.
#pragma unroll
    for (int jj = 0; jj < 4; ++jj)
      Aout[zb + (size_t)jj * TSTEPS + t] = av[jj];
    if (t + 1 < TSTEPS) {
#pragma unroll
      for (int jj = 0; jj < 4; ++jj) zv[jj] = Z[zb + (size_t)jj * TSTEPS + t + 1];
    }
  }
}

// Softmax over the batch axis m for each (n,t), in place.
__global__ __launch_bounds__(256, 2) void softmax_m(float* __restrict__ Y) {
  const int idx = blockIdx.x * 256 + threadIdx.x;
  const int n = idx >> 10;
  const int t = idx & 1023;
  float* base = Y + (size_t)n * MT + t;
  float v[64];
  float mx = -3.0e38f;
#pragma unroll
  for (int m = 0; m < 64; ++m) {
    v[m] = base[(size_t)m * TSTEPS];
    mx = fmaxf(mx, v[m]);
  }
  float s = 0.0f;
#pragma unroll
  for (int m = 0; m < 64; ++m) {
    v[m] = __expf(v[m] - mx);
    s += v[m];
  }
  const float inv = 1.0f / s;
#pragma unroll
  for (int m = 0; m < 64; ++m) base[(size_t)m * TSTEPS] = v[m] * inv;
}

extern "C" void kernel_launch(void* const* d_in, const int* in_sizes, int n_in,
                              void* d_out, int out_size, void* d_ws, size_t ws_size,
                              hipStream_t stream) {
  const float* x   = (const float*)d_in[0];
  const float* a0  = (const float*)d_in[1];
  const float* Waa = (const float*)d_in[2];
  const float* Wax = (const float*)d_in[3];
  const float* Wya = (const float*)d_in[4];
  const float* ba  = (const float*)d_in[5];
  // by (d_in[6]) cancels under softmax over the batch axis.

  float* A = (float*)d_out;    // final a_next [n][m][t]
  float* Y = A + (size_t)ASZ;  // staging for Z, then logits/y [n][m][t]

  unsigned* flags = (unsigned*)d_ws;          // 32 x 64B epoch slots
  float* pp = (float*)((char*)d_ws + 4096);   // 2 x 4 x PPC floats (256 KB)

  hipMemsetAsync(d_ws, 0, 4096, stream);

  // Phase 1: Z = Wax @ X + ba  -> Y region (read-only input for the scan)
  wgemm<<<dim3(256, 8), 256, 0, stream>>>(Wax, x, ba, Y);

  // Phase 2: a_t = tanh(Waa@a_{t-1} + Z_t) -> A region
  {
    void* args[] = {(void*)&Waa, (void*)&a0, (void*)&Y, (void*)&A,
                    (void*)&pp, (void*)&flags};
    hipLaunchCooperativeKernel((const void*)scan_kernel, dim3(32), dim3(256),
                               args, 0, stream);
  }

  // Phase 3: logits = Wya @ A -> Y region (overwrites Z, which is dead)
  wgemm<<<dim3(256, 8), 256, 0, stream>>>(Wya, A, (const float*)nullptr, Y);

  // Phase 4: softmax over batch axis, in place.
  softmax_m<<<2048, 256, 0, stream>>>(Y);
}